// Round 2
// baseline (245.365 us; speedup 1.0000x reference)
//
#include <hip/hip_runtime.h>

typedef unsigned short u16;
typedef short bf16x8 __attribute__((ext_vector_type(8)));
typedef float f32x4 __attribute__((ext_vector_type(4)));

#define CM 256
#define CH 32
#define CZ 128

__device__ inline u16 f2bf(float f) {
    union { float f; unsigned u; } v; v.f = f;
    unsigned r = v.u + 0x7fffu + ((v.u >> 16) & 1u);
    return (u16)(r >> 16);
}

// ---------------------------------------------------------------------------
// Kernel A: LayerNorm + dual projection (a = mn@Wa+ba, b = mn@Wb+bb) * mask.
// 32 rows (s,i) per block of 256 threads (grid 1024). Projection via MFMA:
// M=32 rows, K=256 (c_m), N=64 ([Wa cols | Wb cols]).
// Outputs stored transposed: a_t[(i*32+c)*128 + s] (bf16) so stage-2 MFMA
// fragments are contiguous in k=s.
// LDS: 32*264*2 + 64*264*2 = 50,688 B  (<= 64 KB limit)
// ---------------------------------------------------------------------------
__global__ __launch_bounds__(256, 2) void kA(
    const float* __restrict__ m, const float* __restrict__ mask,
    const float* __restrict__ ln_g, const float* __restrict__ ln_b,
    const float* __restrict__ Wa, const float* __restrict__ ba,
    const float* __restrict__ Wb, const float* __restrict__ bb,
    u16* __restrict__ a_t, u16* __restrict__ b_t)
{
    __shared__ u16 mn_s[32 * 264];   // [row][k], stride 264 (pad 8) bf16
    __shared__ u16 W_s[64 * 264];    // [n][k] transposed weights, n<32:Wa n>=32:Wb

    const int t = threadIdx.x;
    const int w = t >> 6, lane = t & 63, quad = lane >> 4, lr = lane & 15;

    // stage weights transposed into LDS as bf16 (coalesced fp32 reads)
    for (int q = 0; q < 32; q++) {
        int f = q * 256 + t;          // 0..8191 over [256][32]
        int k = f >> 5, c = f & 31;
        W_s[c * 264 + k]        = f2bf(Wa[f]);
        W_s[(c + 32) * 264 + k] = f2bf(Wb[f]);
    }

    const float4 g4  = ((const float4*)ln_g)[lane];
    const float4 be4 = ((const float4*)ln_b)[lane];

    // LayerNorm: each wave handles 8 rows
    for (int rr = 0; rr < 8; rr++) {
        int r = w * 8 + rr;
        int row = blockIdx.x * 32 + r;
        float4 x = ((const float4*)m)[row * 64 + lane];
        float s1 = x.x + x.y + x.z + x.w;
        float s2 = x.x * x.x + x.y * x.y + x.z * x.z + x.w * x.w;
        for (int off = 32; off; off >>= 1) {
            s1 += __shfl_xor(s1, off);
            s2 += __shfl_xor(s2, off);
        }
        float mu = s1 * (1.f / CM);
        float var = s2 * (1.f / CM) - mu * mu;
        float rstd = rsqrtf(var + 1e-5f);
        ushort4 o;
        o.x = f2bf((x.x - mu) * rstd * g4.x + be4.x);
        o.y = f2bf((x.y - mu) * rstd * g4.y + be4.y);
        o.z = f2bf((x.z - mu) * rstd * g4.z + be4.z);
        o.w = f2bf((x.w - mu) * rstd * g4.w + be4.w);
        *(ushort4*)(&mn_s[r * 264 + lane * 4]) = o;
    }
    __syncthreads();

    // MFMA projection: wave w computes n-tile w (16 cols) for both m-tiles
    f32x4 acc[2] = {};
    for (int ks = 0; ks < 8; ks++) {
        bf16x8 wf = *(const bf16x8*)(&W_s[(w * 16 + lr) * 264 + ks * 32 + quad * 8]);
        for (int mt = 0; mt < 2; mt++) {
            bf16x8 af = *(const bf16x8*)(&mn_s[(mt * 16 + lr) * 264 + ks * 32 + quad * 8]);
            acc[mt] = __builtin_amdgcn_mfma_f32_16x16x32_bf16(af, wf, acc[mt], 0, 0, 0);
        }
    }

    // epilogue: bias, mask, store transposed bf16
    const int n = w * 16 + lr;          // C/D col = lane&15
    const int cc = n & 31;
    const bool isB = n >= 32;
    const float bv = isB ? bb[cc] : ba[cc];
    u16* dst = isB ? b_t : a_t;
    for (int mt = 0; mt < 2; mt++)
        for (int reg = 0; reg < 4; reg++) {
            int r = mt * 16 + quad * 4 + reg;   // C/D row = quad*4+reg
            int row = blockIdx.x * 32 + r;
            int s = row >> 8, i = row & 255;
            float val = (acc[mt][reg] + bv) * mask[row];
            dst[(i * 32 + cc) * 128 + s] = f2bf(val);
        }
}

// ---------------------------------------------------------------------------
// Kernel W: transpose Wo [1024][128] fp32 -> Wo_t [128][1024] bf16
// ---------------------------------------------------------------------------
__global__ void kW(const float* __restrict__ Wo, u16* __restrict__ Wo_t)
{
    int f = blockIdx.x * 256 + threadIdx.x;   // f = ce*128 + z
    int ce = f >> 7, z = f & 127;
    Wo_t[z * 1024 + ce] = f2bf(Wo[f]);
}

// ---------------------------------------------------------------------------
// Kernel B: fused outer-product (stage 2) + Wo projection (stage 3).
// Block = 256 thr (4 waves). Tile: 4 i's x 4 j's -> outer tile 128x128
// (K=s=128, staged in two 64-wide K-halves to fit the 64 KB LDS cap);
// each wave computes a 64x64 quadrant. Outer tile round-trips through LDS
// as bf16 in stage-3 A-layout [p=(i_l*4+j_l)][ce=c*32+e], then a
// M=16, K=1024, N=128 GEMM vs Wo_t.
// LDS: 2*128*72*2 = 36,864 B (+1,088 B norm)  (<= 64 KB limit)
// ---------------------------------------------------------------------------
__global__ __launch_bounds__(256, 2) void kB(
    const u16* __restrict__ a_t, const u16* __restrict__ b_t,
    const u16* __restrict__ Wo_t, const float* __restrict__ bo,
    const float* __restrict__ mask, float* __restrict__ out)
{
    __shared__ __align__(16) u16 smem[2 * 128 * 72];  // a_s | b_s, stride 72 bf16
    __shared__ float norm_s[16];
    __shared__ float normp[256];
    u16* a_s = smem;
    u16* b_s = smem + 128 * 72;
    u16* outer_s = smem;                 // overlay after stage 2: [16][1032] = 33,024 B

    const int t = threadIdx.x;
    const int w = t >> 6, lane = t & 63, quad = lane >> 4, lr = lane & 15;
    const int i0 = blockIdx.x * 4, j0 = blockIdx.y * 4;
    const u16* ag = a_t + blockIdx.x * 16384;   // rows i0*32 .. i0*32+128, 128 s each
    const u16* bg = b_t + blockIdx.y * 16384;

    // norm partials: norm[i,j] = sum_s mask[s,i]*mask[s,j] + eps
    {
        int p = t & 15, q = t >> 4;
        int ii = i0 + (p >> 2), jj = j0 + (p & 3);
        float acc = 0.f;
        for (int s = q * 8; s < q * 8 + 8; s++)
            acc += mask[s * 256 + ii] * mask[s * 256 + jj];
        normp[t] = acc;
    }

    // ---- stage 2: outer tile in two K-halves; wave (wm,wn) -> 64x64 quadrant ----
    const int wm = w >> 1, wn = w & 1;
    f32x4 acc2[4][4] = {};
    for (int kh = 0; kh < 2; kh++) {
        for (int q = 0; q < 4; q++) {
            int flat = q * 2048 + t * 8;          // 8192 el per matrix per half
            int mm = flat >> 6, kk = flat & 63;
            *(uint4*)(&a_s[mm * 72 + kk]) = *(const uint4*)(ag + mm * 128 + kh * 64 + kk);
            *(uint4*)(&b_s[mm * 72 + kk]) = *(const uint4*)(bg + mm * 128 + kh * 64 + kk);
        }
        __syncthreads();
        if (kh == 0 && t < 16) {
            float acc = 1e-3f;
            for (int q = 0; q < 16; q++) acc += normp[q * 16 + t];
            norm_s[t] = acc;
        }
        for (int ks = 0; ks < 2; ks++) {
            int k0 = ks * 32 + quad * 8;
            bf16x8 af[4], bf[4];
            for (int tm = 0; tm < 4; tm++)
                af[tm] = *(const bf16x8*)(&a_s[(wm * 64 + tm * 16 + lr) * 72 + k0]);
            for (int tn = 0; tn < 4; tn++)
                bf[tn] = *(const bf16x8*)(&b_s[(wn * 64 + tn * 16 + lr) * 72 + k0]);
            for (int tm = 0; tm < 4; tm++)
                for (int tn = 0; tn < 4; tn++)
                    acc2[tm][tn] = __builtin_amdgcn_mfma_f32_16x16x32_bf16(
                        af[tm], bf[tn], acc2[tm][tn], 0, 0, 0);
        }
        __syncthreads();   // also protects a_s/b_s before restage / overlay
    }

    // write outer tile to LDS in stage-3 A layout, bf16
    for (int tm = 0; tm < 4; tm++)
        for (int tn = 0; tn < 4; tn++)
            for (int reg = 0; reg < 4; reg++) {
                int m_loc = wm * 64 + tm * 16 + quad * 4 + reg;   // i_l*32 + c
                int n_loc = wn * 64 + tn * 16 + lr;               // j_l*32 + e
                int p  = ((m_loc >> 5) << 2) + (n_loc >> 5);      // i_l*4 + j_l
                int ce = ((m_loc & 31) << 5) + (n_loc & 31);      // c*32 + e
                outer_s[p * 1032 + ce] = f2bf(acc2[tm][tn][reg]);
            }
    __syncthreads();

    // ---- stage 3: [16 pairs x 1024] @ Wo_t^T -> [16 x 128] ----
    const int n0w = w * 32;
    f32x4 acc3[2] = {};
    for (int ks = 0; ks < 32; ks++) {
        int k0 = ks * 32 + quad * 8;
        bf16x8 a3 = *(const bf16x8*)(&outer_s[lr * 1032 + k0]);
        for (int tt = 0; tt < 2; tt++) {
            bf16x8 b3 = *(const bf16x8*)(&Wo_t[(n0w + tt * 16 + lr) * 1024 + k0]);
            acc3[tt] = __builtin_amdgcn_mfma_f32_16x16x32_bf16(a3, b3, acc3[tt], 0, 0, 0);
        }
    }

    // epilogue: + bo, / norm
    for (int tt = 0; tt < 2; tt++)
        for (int reg = 0; reg < 4; reg++) {
            int p = quad * 4 + reg;
            int z = n0w + tt * 16 + lr;
            int ii = i0 + (p >> 2), jj = j0 + (p & 3);
            out[(ii * 256 + jj) * 128 + z] = (acc3[tt][reg] + bo[z]) / norm_s[p];
        }
}

extern "C" void kernel_launch(void* const* d_in, const int* in_sizes, int n_in,
                              void* d_out, int out_size, void* d_ws, size_t ws_size,
                              hipStream_t stream)
{
    const float* m    = (const float*)d_in[0];
    const float* mask = (const float*)d_in[1];
    const float* ln_g = (const float*)d_in[2];
    const float* ln_b = (const float*)d_in[3];
    const float* Wa   = (const float*)d_in[4];
    const float* ba   = (const float*)d_in[5];
    const float* Wb   = (const float*)d_in[6];
    const float* bb   = (const float*)d_in[7];
    const float* Wo   = (const float*)d_in[8];
    const float* bo   = (const float*)d_in[9];
    float* out = (float*)d_out;

    char* ws = (char*)d_ws;
    u16* a_t  = (u16*)ws;                       // 2 MB: [8192][128] bf16
    u16* b_t  = (u16*)(ws + (1u << 21));        // 2 MB
    u16* Wo_t = (u16*)(ws + (1u << 22));        // 256 KB: [128][1024] bf16

    hipLaunchKernelGGL(kA, dim3(1024), dim3(256), 0, stream,
                       m, mask, ln_g, ln_b, Wa, ba, Wb, bb, a_t, b_t);
    hipLaunchKernelGGL(kW, dim3(512), dim3(256), 0, stream, Wo, Wo_t);
    hipLaunchKernelGGL(kB, dim3(64, 64), dim3(256), 0, stream,
                       a_t, b_t, Wo_t, bo, mask, out);
}

// Round 3
// 199.738 us; speedup vs baseline: 1.2284x; 1.2284x over previous
//
#include <hip/hip_runtime.h>

typedef unsigned short u16;
typedef short bf16x8 __attribute__((ext_vector_type(8)));
typedef float f32x4 __attribute__((ext_vector_type(4)));

#define CM 256

__device__ inline u16 f2bf(float f) {
    union { float f; unsigned u; } v; v.f = f;
    unsigned r = v.u + 0x7fffu + ((v.u >> 16) & 1u);
    return (u16)(r >> 16);
}

// ---------------------------------------------------------------------------
// kW: one-time weight prep.
//  - Wo[1024 ce][128 z] fp32  ->  Wo_t[z][k'] bf16, with k' = e*32 + c
//    (k-permutation so kB's epilogue can pack 4 consecutive c into ushort4;
//     any k-order works as long as A and B agree).
//  - Wa/Wb[256 k][32 n] fp32  ->  Wab_t[n][256 k] bf16 (n<32: Wa, else Wb)
// ---------------------------------------------------------------------------
__global__ void kW(const float* __restrict__ Wo, const float* __restrict__ Wa,
                   const float* __restrict__ Wb, u16* __restrict__ Wo_t,
                   u16* __restrict__ Wab_t)
{
    int bid = blockIdx.x, t = threadIdx.x;
    if (bid < 512) {
        int idx = bid * 256 + t;            // idx = ce*128 + z (coalesced read)
        int ce = idx >> 7, z = idx & 127;
        int c = ce >> 5, e = ce & 31;
        Wo_t[z * 1024 + e * 32 + c] = f2bf(Wo[idx]);
    } else {
        int idx = (bid - 512) * 256 + t;    // idx = n*256 + k (coalesced write)
        int n = idx >> 8, k = idx & 255;
        float v = (n < 32) ? Wa[k * 32 + n] : Wb[k * 32 + (n - 32)];
        Wab_t[idx] = f2bf(v);
    }
}

// ---------------------------------------------------------------------------
// kN: norm[i][j] = eps + sum_s mask[s,i]*mask[s,j]  (256 blocks x 256 thr)
// ---------------------------------------------------------------------------
__global__ void kN(const float* __restrict__ mask, float* __restrict__ norm_ws)
{
    int i = blockIdx.x, j = threadIdx.x;
    float acc = 1e-3f;
    for (int s = 0; s < 128; s++)
        acc += mask[s * 256 + i] * mask[s * 256 + j];
    norm_ws[i * 256 + j] = acc;
}

// ---------------------------------------------------------------------------
// kA: LayerNorm + dual projection, W-frags direct from pre-transposed Wab_t.
// 64 rows (one s, 64 i's) per block of 256 threads (grid 512).
// Outputs transposed: a_t[(i*32+c)*128 + s] bf16.
// LDS: 64*264*2 = 33,792 B
// ---------------------------------------------------------------------------
__global__ __launch_bounds__(256, 2) void kA(
    const float* __restrict__ m, const float* __restrict__ mask,
    const float* __restrict__ ln_g, const float* __restrict__ ln_b,
    const u16* __restrict__ Wab_t, const float* __restrict__ ba,
    const float* __restrict__ bb,
    u16* __restrict__ a_t, u16* __restrict__ b_t)
{
    __shared__ u16 mn_s[64 * 264];   // [row][k], stride 264 (pad 8)

    const int t = threadIdx.x;
    const int w = t >> 6, lane = t & 63, quad = lane >> 4, lr = lane & 15;
    const int r0 = blockIdx.x * 64;

    // W fragments straight from global (L2-hot, 8 x b128 per thread)
    bf16x8 wf[8];
    for (int ks = 0; ks < 8; ks++)
        wf[ks] = *(const bf16x8*)(Wab_t + (w * 16 + lr) * 256 + ks * 32 + quad * 8);

    const float4 g4  = ((const float4*)ln_g)[lane];
    const float4 be4 = ((const float4*)ln_b)[lane];

    for (int rr = 0; rr < 16; rr++) {
        int r = w * 16 + rr;
        float4 x = ((const float4*)m)[(r0 + r) * 64 + lane];
        float s1 = x.x + x.y + x.z + x.w;
        float s2 = x.x * x.x + x.y * x.y + x.z * x.z + x.w * x.w;
        for (int off = 32; off; off >>= 1) {
            s1 += __shfl_xor(s1, off);
            s2 += __shfl_xor(s2, off);
        }
        float mu = s1 * (1.f / CM);
        float rstd = rsqrtf(s2 * (1.f / CM) - mu * mu + 1e-5f);
        ushort4 o;
        o.x = f2bf((x.x - mu) * rstd * g4.x + be4.x);
        o.y = f2bf((x.y - mu) * rstd * g4.y + be4.y);
        o.z = f2bf((x.z - mu) * rstd * g4.z + be4.z);
        o.w = f2bf((x.w - mu) * rstd * g4.w + be4.w);
        *(ushort4*)(&mn_s[r * 264 + lane * 4]) = o;
    }
    __syncthreads();

    f32x4 acc[4] = {};
    for (int ks = 0; ks < 8; ks++)
        for (int mt = 0; mt < 4; mt++) {
            bf16x8 af = *(const bf16x8*)(&mn_s[(mt * 16 + lr) * 264 + ks * 32 + quad * 8]);
            acc[mt] = __builtin_amdgcn_mfma_f32_16x16x32_bf16(af, wf[ks], acc[mt], 0, 0, 0);
        }

    const int n = w * 16 + lr;        // C/D col
    const int cc = n & 31;
    const bool isB = n >= 32;
    const float bv = isB ? bb[cc] : ba[cc];
    u16* dst = isB ? b_t : a_t;
    for (int mt = 0; mt < 4; mt++)
        for (int reg = 0; reg < 4; reg++) {
            int r = mt * 16 + quad * 4 + reg;       // C/D row
            int row = r0 + r;
            int s = row >> 8, i = row & 255;
            float val = (acc[mt][reg] + bv) * mask[row];
            dst[(i * 32 + cc) * 128 + s] = f2bf(val);
        }
}

// ---------------------------------------------------------------------------
// kB: fused outer-product + Wo projection. Tile: 4 i x 8 j (32 pairs).
// Grid (64,32), block 256 (4 waves: wm = w>>1 over 128 a-rows, wn = w&1 over
// 256 b-rows). Stage 2 in two K=64 halves; acc2[4][8]. Outer tile goes to
// LDS as bf16 [32 p][1024 k'] with chunk swizzle f = (chunk*5 + p) & 127
// (a3 reads 2-way conflict-free; epilogue packs ushort4 thanks to k'=e*32+c).
// Stage 3: M=32, K=1024, N=128 (n-slice 32 per wave), depth-2 Wo_t prefetch.
// LDS: max(55,296, 65,536) = 65,536 B exactly.
// ---------------------------------------------------------------------------
__global__ __launch_bounds__(256, 2) void kB(
    const u16* __restrict__ a_t, const u16* __restrict__ b_t,
    const u16* __restrict__ Wo_t, const float* __restrict__ bo,
    const float* __restrict__ norm_ws, float* __restrict__ out)
{
    __shared__ __align__(16) u16 smem[32768];     // 65,536 B
    u16* a_s = smem;                  // [128][72]
    u16* b_s = smem + 128 * 72;       // [256][72]
    u16* outer_s = smem;              // overlay: [32][1024]

    const int t = threadIdx.x;
    const int w = t >> 6, lane = t & 63, quad = lane >> 4, lr = lane & 15;
    const int wm = w >> 1, wn = w & 1;
    const u16* ag = a_t + blockIdx.x * (128 * 128);
    const u16* bg = b_t + blockIdx.y * (256 * 128);

    // ---- stage 2 ----
    f32x4 acc2[4][8] = {};
    for (int kh = 0; kh < 2; kh++) {
        for (int q = 0; q < 4; q++) {
            int flat = q * 2048 + t * 8;
            int mm = flat >> 6, kk = flat & 63;
            *(uint4*)(&a_s[mm * 72 + kk]) = *(const uint4*)(ag + mm * 128 + kh * 64 + kk);
        }
        for (int q = 0; q < 8; q++) {
            int flat = q * 2048 + t * 8;
            int mm = flat >> 6, kk = flat & 63;
            *(uint4*)(&b_s[mm * 72 + kk]) = *(const uint4*)(bg + mm * 128 + kh * 64 + kk);
        }
        __syncthreads();
        for (int ks = 0; ks < 2; ks++) {
            int k0 = ks * 32 + quad * 8;
            bf16x8 af[4], bfr[8];
            for (int tm = 0; tm < 4; tm++)
                af[tm] = *(const bf16x8*)(&a_s[(wm * 64 + tm * 16 + lr) * 72 + k0]);
            for (int tn = 0; tn < 8; tn++)
                bfr[tn] = *(const bf16x8*)(&b_s[(wn * 128 + tn * 16 + lr) * 72 + k0]);
            for (int tm = 0; tm < 4; tm++)
                for (int tn = 0; tn < 8; tn++)
                    acc2[tm][tn] = __builtin_amdgcn_mfma_f32_16x16x32_bf16(
                        af[tm], bfr[tn], acc2[tm][tn], 0, 0, 0);
        }
        __syncthreads();
    }

    // ---- epilogue stage 2: write outer tile, swizzled bf16 ----
    for (int tm = 0; tm < 4; tm++) {
        int mbase = wm * 64 + tm * 16 + quad * 4;      // c-base, 4-aligned
        int i_l = mbase >> 5, cb = mbase & 31;
        for (int tn = 0; tn < 8; tn++) {
            int n_loc = wn * 128 + tn * 16 + lr;
            int j_l = n_loc >> 5, e = n_loc & 31;
            int p = i_l * 8 + j_l;
            int cI = e * 4 + (cb >> 3);
            int f = (cI * 5 + p) & 127;
            ushort4 o;
            o.x = f2bf(acc2[tm][tn][0]);
            o.y = f2bf(acc2[tm][tn][1]);
            o.z = f2bf(acc2[tm][tn][2]);
            o.w = f2bf(acc2[tm][tn][3]);
            *(ushort4*)(&outer_s[p * 1024 + f * 8 + (cb & 7)]) = o;
        }
    }
    __syncthreads();

    // ---- stage 3: [32 p][1024 k'] @ Wo_t -> [32 p][128 z] ----
    const int n0w = w * 32;
    const u16* wp0 = Wo_t + (n0w + lr) * 1024;
    const u16* wp1 = Wo_t + (n0w + 16 + lr) * 1024;
    f32x4 acc3[2][2] = {};
    bf16x8 b3c[2], b3n[2];
    {
        int k0 = quad * 8;
        b3c[0] = *(const bf16x8*)(wp0 + k0);
        b3c[1] = *(const bf16x8*)(wp1 + k0);
        b3n[0] = *(const bf16x8*)(wp0 + 32 + k0);
        b3n[1] = *(const bf16x8*)(wp1 + 32 + k0);
    }
    for (int ks = 0; ks < 32; ks++) {
        int cI = ks * 4 + quad;
        bf16x8 a3[2];
        for (int mt = 0; mt < 2; mt++) {
            int p = mt * 16 + lr;
            int f = (cI * 5 + p) & 127;
            a3[mt] = *(const bf16x8*)(&outer_s[p * 1024 + f * 8]);
        }
        bf16x8 pf0, pf1;
        if (ks < 30) {
            int k2 = (ks + 2) * 32 + quad * 8;
            pf0 = *(const bf16x8*)(wp0 + k2);
            pf1 = *(const bf16x8*)(wp1 + k2);
        }
        for (int mt = 0; mt < 2; mt++) {
            acc3[mt][0] = __builtin_amdgcn_mfma_f32_16x16x32_bf16(a3[mt], b3c[0], acc3[mt][0], 0, 0, 0);
            acc3[mt][1] = __builtin_amdgcn_mfma_f32_16x16x32_bf16(a3[mt], b3c[1], acc3[mt][1], 0, 0, 0);
        }
        b3c[0] = b3n[0]; b3c[1] = b3n[1];
        b3n[0] = pf0;    b3n[1] = pf1;
    }

    // ---- epilogue: + bo, / norm, store ----
    const int i0 = blockIdx.x * 4, j0 = blockIdx.y * 8;
    for (int mt = 0; mt < 2; mt++)
        for (int reg = 0; reg < 4; reg++) {
            int p = mt * 16 + quad * 4 + reg;
            int ii = i0 + (p >> 3), jj = j0 + (p & 7);
            float nrm = norm_ws[ii * 256 + jj];
            for (int tt = 0; tt < 2; tt++) {
                int z = n0w + tt * 16 + lr;
                out[(ii * 256 + jj) * 128 + z] = (acc3[mt][tt][reg] + bo[z]) / nrm;
            }
        }
}

extern "C" void kernel_launch(void* const* d_in, const int* in_sizes, int n_in,
                              void* d_out, int out_size, void* d_ws, size_t ws_size,
                              hipStream_t stream)
{
    const float* m    = (const float*)d_in[0];
    const float* mask = (const float*)d_in[1];
    const float* ln_g = (const float*)d_in[2];
    const float* ln_b = (const float*)d_in[3];
    const float* Wa   = (const float*)d_in[4];
    const float* ba   = (const float*)d_in[5];
    const float* Wb   = (const float*)d_in[6];
    const float* bb   = (const float*)d_in[7];
    const float* Wo   = (const float*)d_in[8];
    const float* bo   = (const float*)d_in[9];
    float* out = (float*)d_out;

    char* ws = (char*)d_ws;
    u16*   a_t     = (u16*)ws;                        // 2 MB
    u16*   b_t     = (u16*)(ws + 0x200000);           // 2 MB
    u16*   Wo_t    = (u16*)(ws + 0x400000);           // 256 KB
    u16*   Wab_t   = (u16*)(ws + 0x440000);           // 32 KB
    float* norm_ws = (float*)(ws + 0x448000);         // 256 KB

    hipLaunchKernelGGL(kW, dim3(576), dim3(256), 0, stream, Wo, Wa, Wb, Wo_t, Wab_t);
    hipLaunchKernelGGL(kN, dim3(256), dim3(256), 0, stream, mask, norm_ws);
    hipLaunchKernelGGL(kA, dim3(512), dim3(256), 0, stream,
                       m, mask, ln_g, ln_b, Wab_t, ba, bb, a_t, b_t);
    hipLaunchKernelGGL(kB, dim3(64, 32), dim3(256), 0, stream,
                       a_t, b_t, Wo_t, bo, norm_ws, out);
}